// Round 1
// baseline (9072.296 us; speedup 1.0000x reference)
//
#include <hip/hip_runtime.h>
#include <hip/hip_bf16.h>
#include <cmath>

#define D_MODEL 2048
#define N_HEADS 16
#define D_HEAD  128
#define FFDIM   8192
#define BATCH   2
#define SEQ     2048
#define TOKENS  (BATCH * SEQ)

using bf16 = __hip_bfloat16;
typedef __bf16 v8bf __attribute__((ext_vector_type(8)));
typedef float  v4f  __attribute__((ext_vector_type(4)));

// ---------------- weight cast f32 -> bf16 ----------------
__global__ __launch_bounds__(256) void cast_kernel(const float* __restrict__ in,
                                                   bf16* __restrict__ out, int n4) {
    int i = blockIdx.x * 256 + threadIdx.x;
    if (i < n4) {
        float4 f = ((const float4*)in)[i];
        int o = i * 4;
        out[o + 0] = __float2bfloat16(f.x);
        out[o + 1] = __float2bfloat16(f.y);
        out[o + 2] = __float2bfloat16(f.z);
        out[o + 3] = __float2bfloat16(f.w);
    }
}

// ---------------- LayerNorm (one row per block), fp32 in -> bf16 out ----------------
__global__ __launch_bounds__(256) void ln_kernel(const float* __restrict__ x,
                                                 const float* __restrict__ g,
                                                 const float* __restrict__ b,
                                                 bf16* __restrict__ out) {
    int row = blockIdx.x;
    int t = threadIdx.x;
    const float* xr = x + (size_t)row * D_MODEL;
    float v[8];
    float s = 0.f, s2 = 0.f;
#pragma unroll
    for (int i = 0; i < 8; i++) {
        float val = xr[t + 256 * i];
        v[i] = val;
        s += val;
        s2 += val * val;
    }
#pragma unroll
    for (int off = 32; off > 0; off >>= 1) {
        s  += __shfl_down(s, off, 64);
        s2 += __shfl_down(s2, off, 64);
    }
    __shared__ float ws1[4], ws2[4];
    int wv = t >> 6;
    if ((t & 63) == 0) { ws1[wv] = s; ws2[wv] = s2; }
    __syncthreads();
    float fs  = ws1[0] + ws1[1] + ws1[2] + ws1[3];
    float fs2 = ws2[0] + ws2[1] + ws2[2] + ws2[3];
    float mean = fs * (1.0f / D_MODEL);
    float var  = fs2 * (1.0f / D_MODEL) - mean * mean;
    float rstd = rsqrtf(var + 1e-5f);
    bf16* orow = out + (size_t)row * D_MODEL;
#pragma unroll
    for (int i = 0; i < 8; i++) {
        int c = t + 256 * i;
        orow[c] = __float2bfloat16((v[i] - mean) * rstd * g[c] + b[c]);
    }
}

// ---------------- RoPE in-place on fp32 qkv (q and k) ----------------
__global__ __launch_bounds__(256) void rope_kernel(float* __restrict__ qkv) {
    int unit = blockIdx.x * 4 + (threadIdx.x >> 6); // (token, head) unit
    int j = threadIdx.x & 63;
    int h = unit & (N_HEADS - 1);
    int tok = unit >> 4;
    int pos = tok & (SEQ - 1);
    float invf = powf(10000.0f, -(float)j / 64.0f);
    float ang = (float)pos * invf;
    float c = cosf(ang), s = sinf(ang);
    size_t base = (size_t)tok * (3 * D_MODEL) + h * D_HEAD;
    float q1 = qkv[base + j], q2 = qkv[base + j + 64];
    qkv[base + j]      = q1 * c - q2 * s;
    qkv[base + j + 64] = q2 * c + q1 * s;
    size_t kb = base + D_MODEL;
    float k1 = qkv[kb + j], k2 = qkv[kb + j + 64];
    qkv[kb + j]      = k1 * c - k2 * s;
    qkv[kb + j + 64] = k2 * c + k1 * s;
}

// ---------------- causal attention, one block per (b,h,q), fp32 -> bf16 out ----------------
__global__ __launch_bounds__(256) void attn_kernel(const float* __restrict__ qkv,
                                                   bf16* __restrict__ att) {
    __shared__ __align__(16) float qv[D_HEAD];
    __shared__ float sc[SEQ];
    __shared__ float red[256];
    int bh   = blockIdx.x / SEQ;
    int qpos = blockIdx.x - bh * SEQ;
    int b = bh >> 4, h = bh & 15;
    int t = threadIdx.x;

    size_t qbase = ((size_t)b * SEQ + qpos) * (3 * D_MODEL) + h * D_HEAD;
    if (t < D_HEAD) qv[t] = qkv[qbase + t];
    __syncthreads();

    int nk = qpos + 1;
    float lmax = -1e30f;
    for (int k = t; k < nk; k += 256) {
        const float4* kp = (const float4*)(qkv + ((size_t)b * SEQ + k) * (3 * D_MODEL) + D_MODEL + h * D_HEAD);
        const float4* qp = (const float4*)qv;
        float d = 0.f;
#pragma unroll
        for (int i = 0; i < D_HEAD / 4; i++) {
            float4 k4 = kp[i];
            float4 q4 = qp[i];
            d += q4.x * k4.x + q4.y * k4.y + q4.z * k4.z + q4.w * k4.w;
        }
        d *= 0.08838834764831845f; // 1/sqrt(128)
        sc[k] = d;
        lmax = fmaxf(lmax, d);
    }
    red[t] = lmax;
    __syncthreads();
#pragma unroll
    for (int s = 128; s > 0; s >>= 1) {
        if (t < s) red[t] = fmaxf(red[t], red[t + s]);
        __syncthreads();
    }
    float m = red[0];
    __syncthreads();

    float lsum = 0.f;
    for (int k = t; k < nk; k += 256) {
        float p = __expf(sc[k] - m);
        sc[k] = p;
        lsum += p;
    }
    red[t] = lsum;
    __syncthreads();
#pragma unroll
    for (int s = 128; s > 0; s >>= 1) {
        if (t < s) red[t] += red[t + s];
        __syncthreads();
    }
    float inv = 1.0f / red[0];
    __syncthreads();

    // PV: 2-way split over keys, d = t&127
    int d = t & 127;
    int half = t >> 7;
    const float* vp = qkv + (size_t)b * SEQ * (3 * D_MODEL) + 2 * D_MODEL + h * D_HEAD + d;
    float o = 0.f;
    for (int k = half; k < nk; k += 2) o += sc[k] * vp[(size_t)k * (3 * D_MODEL)];
    red[t] = o;
    __syncthreads();
    if (t < 128) {
        float val = (red[t] + red[t + 128]) * inv;
        att[((size_t)b * SEQ + qpos) * D_MODEL + h * D_HEAD + t] = __float2bfloat16(val);
    }
}

// ---------------- bf16 MFMA GEMM: C[M,N] = A[M,K] @ W[N,K]^T (+ epilogue) ----------------
// EPI 0: plain -> fp32 out
// EPI 1: + bias + residual -> fp32 out
// EPI 2: + bias, GELU -> bf16 out
#define BM 128
#define BN 128
#define BK 32

template <int EPI>
__global__ __launch_bounds__(256) void gemm_bt(const bf16* __restrict__ A,
                                               const bf16* __restrict__ W,
                                               const float* __restrict__ bias,
                                               const float* __restrict__ res,
                                               float* __restrict__ outF,
                                               bf16* __restrict__ outB,
                                               int M, int N, int K) {
    __shared__ __align__(16) bf16 As[BM * BK];
    __shared__ __align__(16) bf16 Bs[BN * BK];
    int t = threadIdx.x;
    int wave = t >> 6, lane = t & 63;
    int wm = (wave >> 1) * 64;   // wave row offset in tile
    int wn = (wave & 1) * 64;    // wave col offset in tile
    int lr = lane & 15;          // fragment row/col index
    int lq = lane >> 4;          // quad
    int row0 = blockIdx.y * BM;
    int col0 = blockIdx.x * BN;

    v4f acc[4][4] = {};

    for (int k0 = 0; k0 < K; k0 += BK) {
#pragma unroll
        for (int c = t; c < 512; c += 256) {
            int r = c >> 2, ko = (c & 3) * 8;
            *(uint4*)(&As[r * BK + ko]) = *(const uint4*)(&A[(size_t)(row0 + r) * K + k0 + ko]);
            *(uint4*)(&Bs[r * BK + ko]) = *(const uint4*)(&W[(size_t)(col0 + r) * K + k0 + ko]);
        }
        __syncthreads();
        v8bf af[4], bfr[4];
#pragma unroll
        for (int i = 0; i < 4; i++) {
            af[i]  = *(const v8bf*)(&As[(wm + i * 16 + lr) * BK + lq * 8]);
            bfr[i] = *(const v8bf*)(&Bs[(wn + i * 16 + lr) * BK + lq * 8]);
        }
#pragma unroll
        for (int i = 0; i < 4; i++)
#pragma unroll
            for (int j = 0; j < 4; j++)
                acc[i][j] = __builtin_amdgcn_mfma_f32_16x16x32_bf16(af[i], bfr[j], acc[i][j], 0, 0, 0);
        __syncthreads();
    }

#pragma unroll
    for (int i = 0; i < 4; i++) {
#pragma unroll
        for (int j = 0; j < 4; j++) {
#pragma unroll
            for (int r = 0; r < 4; r++) {
                int grow = row0 + wm + i * 16 + lq * 4 + r;
                int gcol = col0 + wn + j * 16 + lr;
                float c = acc[i][j][r];
                size_t idx = (size_t)grow * N + gcol;
                if (EPI == 0) {
                    outF[idx] = c;
                } else if (EPI == 1) {
                    outF[idx] = c + bias[gcol] + res[idx];
                } else { // EPI == 2: bias + exact GELU -> bf16
                    c += bias[gcol];
                    float gel = 0.5f * c * (1.0f + erff(c * 0.7071067811865475f));
                    outB[idx] = __float2bfloat16(gel);
                }
            }
        }
    }
}

extern "C" void kernel_launch(void* const* d_in, const int* in_sizes, int n_in,
                              void* d_out, int out_size, void* d_ws, size_t ws_size,
                              hipStream_t stream) {
    const float* x      = (const float*)d_in[0];
    const float* w_qkv  = (const float*)d_in[1];
    const float* w_proj = (const float*)d_in[2];
    const float* b_proj = (const float*)d_in[3];
    const float* w_ff1  = (const float*)d_in[4];
    const float* b_ff1  = (const float*)d_in[5];
    const float* w_ff2  = (const float*)d_in[6];
    const float* b_ff2  = (const float*)d_in[7];
    const float* g1     = (const float*)d_in[8];
    const float* be1    = (const float*)d_in[9];
    const float* g2     = (const float*)d_in[10];
    const float* be2    = (const float*)d_in[11];
    float* out = (float*)d_out;

    char* ws = (char*)d_ws;
    size_t off = 0;
    auto alloc = [&](size_t bytes) {
        void* p = ws + off;
        off += (bytes + 255) & ~(size_t)255;
        return p;
    };
    bf16*  wqkv_b  = (bf16*)alloc((size_t)3 * D_MODEL * D_MODEL * sizeof(bf16));
    bf16*  wproj_b = (bf16*)alloc((size_t)D_MODEL * D_MODEL * sizeof(bf16));
    bf16*  wff1_b  = (bf16*)alloc((size_t)FFDIM * D_MODEL * sizeof(bf16));
    bf16*  wff2_b  = (bf16*)alloc((size_t)D_MODEL * FFDIM * sizeof(bf16));
    float* qkv_f   = (float*)alloc((size_t)TOKENS * 3 * D_MODEL * sizeof(float));
    bf16*  act_b   = (bf16*)alloc((size_t)TOKENS * D_MODEL * sizeof(bf16)); // h / att / h2 (sequential reuse)
    float* x2_f    = (float*)alloc((size_t)TOKENS * D_MODEL * sizeof(float));
    bf16*  ff1_b   = (bf16*)qkv_f; // overlay: qkv dead after attention; 67MB <= 100MB

    // 1. cast weights to bf16
    cast_kernel<<<(3 * D_MODEL * D_MODEL / 4 + 255) / 256, 256, 0, stream>>>(w_qkv, wqkv_b, 3 * D_MODEL * D_MODEL / 4);
    cast_kernel<<<(D_MODEL * D_MODEL / 4 + 255) / 256, 256, 0, stream>>>(w_proj, wproj_b, D_MODEL * D_MODEL / 4);
    cast_kernel<<<(FFDIM * D_MODEL / 4 + 255) / 256, 256, 0, stream>>>(w_ff1, wff1_b, FFDIM * D_MODEL / 4);
    cast_kernel<<<(D_MODEL * FFDIM / 4 + 255) / 256, 256, 0, stream>>>(w_ff2, wff2_b, D_MODEL * FFDIM / 4);

    // 2. LN1: x -> h (bf16)
    ln_kernel<<<TOKENS, 256, 0, stream>>>(x, g1, be1, act_b);

    // 3. QKV GEMM: qkv = h @ w_qkv^T  (fp32 out)
    gemm_bt<0><<<dim3(3 * D_MODEL / BN, TOKENS / BM), 256, 0, stream>>>(
        act_b, wqkv_b, nullptr, nullptr, qkv_f, nullptr, TOKENS, 3 * D_MODEL, D_MODEL);

    // 4. RoPE in-place on q,k
    rope_kernel<<<TOKENS * N_HEADS / 4, 256, 0, stream>>>(qkv_f);

    // 5. causal attention -> att (bf16, reuse act_b)
    attn_kernel<<<BATCH * N_HEADS * SEQ, 256, 0, stream>>>(qkv_f, act_b);

    // 6. proj GEMM + bias + residual(x) -> x2 (fp32)
    gemm_bt<1><<<dim3(D_MODEL / BN, TOKENS / BM), 256, 0, stream>>>(
        act_b, wproj_b, b_proj, x, x2_f, nullptr, TOKENS, D_MODEL, D_MODEL);

    // 7. LN2: x2 -> h2 (bf16, reuse act_b)
    ln_kernel<<<TOKENS, 256, 0, stream>>>(x2_f, g2, be2, act_b);

    // 8. FF1 GEMM + bias + GELU -> ff1 (bf16, overlays qkv region)
    gemm_bt<2><<<dim3(FFDIM / BN, TOKENS / BM), 256, 0, stream>>>(
        act_b, wff1_b, b_ff1, nullptr, nullptr, ff1_b, TOKENS, FFDIM, D_MODEL);

    // 9. FF2 GEMM + bias + residual(x2) -> out (fp32)
    gemm_bt<1><<<dim3(D_MODEL / BN, TOKENS / BM), 256, 0, stream>>>(
        ff1_b, wff2_b, b_ff2, x2_f, out, nullptr, TOKENS, D_MODEL, FFDIM);

    (void)in_sizes; (void)n_in; (void)out_size; (void)ws_size;
}

// Round 2
// 1108.176 us; speedup vs baseline: 8.1867x; 8.1867x over previous
//
#include <hip/hip_runtime.h>
#include <hip/hip_bf16.h>
#include <cmath>

#define D_MODEL 2048
#define N_HEADS 16
#define D_HEAD  128
#define FFDIM   8192
#define BATCH   2
#define SEQ     2048
#define TOKENS  (BATCH * SEQ)

using bf16 = __hip_bfloat16;
typedef __bf16 v8bf __attribute__((ext_vector_type(8)));
typedef float  v4f  __attribute__((ext_vector_type(4)));

__device__ inline __bf16 f2b(float f) {
    bf16 h = __float2bfloat16(f);
    return *reinterpret_cast<__bf16*>(&h);
}

// ---------------- weight cast f32 -> bf16 ----------------
__global__ __launch_bounds__(256) void cast_kernel(const float* __restrict__ in,
                                                   bf16* __restrict__ out, int n4) {
    int i = blockIdx.x * 256 + threadIdx.x;
    if (i < n4) {
        float4 f = ((const float4*)in)[i];
        int o = i * 4;
        out[o + 0] = __float2bfloat16(f.x);
        out[o + 1] = __float2bfloat16(f.y);
        out[o + 2] = __float2bfloat16(f.z);
        out[o + 3] = __float2bfloat16(f.w);
    }
}

// ---------------- LayerNorm (one row per block), fp32 in -> bf16 out ----------------
__global__ __launch_bounds__(256) void ln_kernel(const float* __restrict__ x,
                                                 const float* __restrict__ g,
                                                 const float* __restrict__ b,
                                                 bf16* __restrict__ out) {
    int row = blockIdx.x;
    int t = threadIdx.x;
    const float* xr = x + (size_t)row * D_MODEL;
    float v[8];
    float s = 0.f, s2 = 0.f;
#pragma unroll
    for (int i = 0; i < 8; i++) {
        float val = xr[t + 256 * i];
        v[i] = val;
        s += val;
        s2 += val * val;
    }
#pragma unroll
    for (int off = 32; off > 0; off >>= 1) {
        s  += __shfl_down(s, off, 64);
        s2 += __shfl_down(s2, off, 64);
    }
    __shared__ float ws1[4], ws2[4];
    int wv = t >> 6;
    if ((t & 63) == 0) { ws1[wv] = s; ws2[wv] = s2; }
    __syncthreads();
    float fs  = ws1[0] + ws1[1] + ws1[2] + ws1[3];
    float fs2 = ws2[0] + ws2[1] + ws2[2] + ws2[3];
    float mean = fs * (1.0f / D_MODEL);
    float var  = fs2 * (1.0f / D_MODEL) - mean * mean;
    float rstd = rsqrtf(var + 1e-5f);
    bf16* orow = out + (size_t)row * D_MODEL;
#pragma unroll
    for (int i = 0; i < 8; i++) {
        int c = t + 256 * i;
        orow[c] = __float2bfloat16((v[i] - mean) * rstd * g[c] + b[c]);
    }
}

// ---------------- RoPE in-place on fp32 qkv (q and k) ----------------
__global__ __launch_bounds__(256) void rope_kernel(float* __restrict__ qkv) {
    int unit = blockIdx.x * 4 + (threadIdx.x >> 6);
    int j = threadIdx.x & 63;
    int h = unit & (N_HEADS - 1);
    int tok = unit >> 4;
    int pos = tok & (SEQ - 1);
    float invf = powf(10000.0f, -(float)j / 64.0f);
    float ang = (float)pos * invf;
    float c = cosf(ang), s = sinf(ang);
    size_t base = (size_t)tok * (3 * D_MODEL) + h * D_HEAD;
    float q1 = qkv[base + j], q2 = qkv[base + j + 64];
    qkv[base + j]      = q1 * c - q2 * s;
    qkv[base + j + 64] = q2 * c + q1 * s;
    size_t kb = base + D_MODEL;
    float k1 = qkv[kb + j], k2 = qkv[kb + j + 64];
    qkv[kb + j]      = k1 * c - k2 * s;
    qkv[kb + j + 64] = k2 * c + k1 * s;
}

// ---------------- V transpose: qkv fp32 [tok][3D] -> Vt bf16 [bh][d][k] ----------------
__global__ __launch_bounds__(256) void vt_kernel(const float* __restrict__ qkv,
                                                 bf16* __restrict__ vt) {
    __shared__ float tile[32][65];
    int bh = blockIdx.x;
    int k0 = blockIdx.y * 64;
    int d0 = blockIdx.z * 32;
    int b = bh >> 4, h = bh & 15;
    int t = threadIdx.x;
    const float* src = qkv + ((size_t)b * SEQ + k0) * (3 * D_MODEL) + 2 * D_MODEL + h * D_HEAD + d0;
#pragma unroll
    for (int i = 0; i < 8; i++) {
        int e = t + 256 * i;
        int kr = e >> 5, dc = e & 31;
        tile[dc][kr] = src[(size_t)kr * (3 * D_MODEL) + dc];
    }
    __syncthreads();
    bf16* dst = vt + ((size_t)bh * D_HEAD + d0) * SEQ + k0;
#pragma unroll
    for (int i = 0; i < 8; i++) {
        int e = t + 256 * i;
        int dr = e >> 6, kc = e & 63;
        dst[(size_t)dr * SEQ + kc] = __float2bfloat16(tile[dr][kc]);
    }
}

// ---------------- flash attention: MFMA, online softmax ----------------
// grid (B*H, S/64); 4 waves, wave w handles 16 q-rows. Q in regs, K/Vt in LDS.
#define KS_STRIDE 136
#define VT_STRIDE 72
#define PS_STRIDE 72

__global__ __launch_bounds__(256) void flash_attn(const float* __restrict__ qkv,
                                                  const bf16* __restrict__ vt,
                                                  bf16* __restrict__ att) {
    __shared__ __align__(16) bf16 Ks[64 * KS_STRIDE];       // [kpos][d] padded
    __shared__ __align__(16) bf16 Vts[D_HEAD * VT_STRIDE];  // [d][kpos] padded
    __shared__ __align__(16) bf16 Ps[4 * 16 * PS_STRIDE];   // per-wave [q][kpos]

    int bh = blockIdx.x;
    int qt = (int)gridDim.y - 1 - (int)blockIdx.y;  // heavy q-tiles first
    int b = bh >> 4, h = bh & 15;
    int t = threadIdx.x, wave = t >> 6, lane = t & 63;
    int lr = lane & 15, lq = lane >> 4;

    // Q fragments, scale folded in
    const float* qp = qkv + ((size_t)b * SEQ + qt * 64 + wave * 16 + lr) * (3 * D_MODEL) + h * D_HEAD;
    v8bf aq[4];
#pragma unroll
    for (int c = 0; c < 4; c++) {
        const float4* q4 = (const float4*)(qp + c * 32 + lq * 8);
        float4 qa = q4[0], qb = q4[1];
        aq[c][0] = f2b(qa.x * 0.08838834764831845f);
        aq[c][1] = f2b(qa.y * 0.08838834764831845f);
        aq[c][2] = f2b(qa.z * 0.08838834764831845f);
        aq[c][3] = f2b(qa.w * 0.08838834764831845f);
        aq[c][4] = f2b(qb.x * 0.08838834764831845f);
        aq[c][5] = f2b(qb.y * 0.08838834764831845f);
        aq[c][6] = f2b(qb.z * 0.08838834764831845f);
        aq[c][7] = f2b(qb.w * 0.08838834764831845f);
    }

    float m_r[4], l_r[4];
    v4f O[8] = {};
#pragma unroll
    for (int r = 0; r < 4; r++) { m_r[r] = -1e30f; l_r[r] = 0.f; }

    int n_tiles = qt + 1;
    for (int kt = 0; kt < n_tiles; kt++) {
        int kv0 = kt * 64;
        __syncthreads();
        // stage K tile (fp32 -> bf16), 64 x 128
        {
            const float* kbase = qkv + ((size_t)b * SEQ + kv0) * (3 * D_MODEL) + D_MODEL + h * D_HEAD;
#pragma unroll
            for (int i = 0; i < 8; i++) {
                int e4 = t + 256 * i;
                int kr = e4 >> 5, c4 = (e4 & 31) * 4;
                float4 f = *(const float4*)(kbase + (size_t)kr * (3 * D_MODEL) + c4);
                bf16* dst = &Ks[kr * KS_STRIDE + c4];
                dst[0] = __float2bfloat16(f.x);
                dst[1] = __float2bfloat16(f.y);
                dst[2] = __float2bfloat16(f.z);
                dst[3] = __float2bfloat16(f.w);
            }
            // stage Vt tile (bf16 copy), 128 x 64
            const bf16* vbase = vt + (size_t)bh * D_HEAD * SEQ + kv0;
#pragma unroll
            for (int i = 0; i < 4; i++) {
                int e8 = t + 256 * i;
                int dr = e8 >> 3, k8 = (e8 & 7) * 8;
                *(uint4*)&Vts[dr * VT_STRIDE + k8] = *(const uint4*)(vbase + (size_t)dr * SEQ + k8);
            }
        }
        __syncthreads();

        // scores S = Q K^T (scaled)
        v4f sc[4];
#pragma unroll
        for (int nt = 0; nt < 4; nt++) {
            v4f a = {};
#pragma unroll
            for (int c = 0; c < 4; c++) {
                v8bf bk = *(const v8bf*)&Ks[(nt * 16 + lr) * KS_STRIDE + c * 32 + lq * 8];
                a = __builtin_amdgcn_mfma_f32_16x16x32_bf16(aq[c], bk, a, 0, 0, 0);
            }
            sc[nt] = a;
        }
        // causal mask on diagonal tile
        if (kt == n_tiles - 1) {
#pragma unroll
            for (int nt = 0; nt < 4; nt++)
#pragma unroll
                for (int r = 0; r < 4; r++) {
                    int cl = nt * 16 + lr, rl = wave * 16 + lq * 4 + r;
                    if (cl > rl) sc[nt][r] = -1e30f;
                }
        }
        // online softmax
        float mt[4];
#pragma unroll
        for (int r = 0; r < 4; r++) {
            float v = fmaxf(fmaxf(sc[0][r], sc[1][r]), fmaxf(sc[2][r], sc[3][r]));
#pragma unroll
            for (int mk = 8; mk >= 1; mk >>= 1) v = fmaxf(v, __shfl_xor(v, mk, 64));
            mt[r] = v;
        }
        float alpha[4];
#pragma unroll
        for (int r = 0; r < 4; r++) {
            float mn = fmaxf(m_r[r], mt[r]);
            alpha[r] = __expf(m_r[r] - mn);
            m_r[r] = mn;
        }
        bf16* pw = &Ps[wave * 16 * PS_STRIDE];
        float rs[4] = {0.f, 0.f, 0.f, 0.f};
#pragma unroll
        for (int nt = 0; nt < 4; nt++)
#pragma unroll
            for (int r = 0; r < 4; r++) {
                float p = __expf(sc[nt][r] - m_r[r]);
                rs[r] += p;
                pw[(lq * 4 + r) * PS_STRIDE + nt * 16 + lr] = __float2bfloat16(p);
            }
#pragma unroll
        for (int r = 0; r < 4; r++) {
            float v = rs[r];
#pragma unroll
            for (int mk = 8; mk >= 1; mk >>= 1) v += __shfl_xor(v, mk, 64);
            l_r[r] = l_r[r] * alpha[r] + v;
        }
#pragma unroll
        for (int jt = 0; jt < 8; jt++)
#pragma unroll
            for (int r = 0; r < 4; r++) O[jt][r] *= alpha[r];

        // wave-private P writes must complete before cross-lane frag reads
        asm volatile("s_waitcnt lgkmcnt(0)" ::: "memory");

        v8bf ap[2];
#pragma unroll
        for (int c = 0; c < 2; c++)
            ap[c] = *(const v8bf*)&pw[lr * PS_STRIDE + c * 32 + lq * 8];
#pragma unroll
        for (int jt = 0; jt < 8; jt++) {
#pragma unroll
            for (int c = 0; c < 2; c++) {
                v8bf bv = *(const v8bf*)&Vts[(jt * 16 + lr) * VT_STRIDE + c * 32 + lq * 8];
                O[jt] = __builtin_amdgcn_mfma_f32_16x16x32_bf16(ap[c], bv, O[jt], 0, 0, 0);
            }
        }
    }

    float inv[4];
#pragma unroll
    for (int r = 0; r < 4; r++) inv[r] = 1.0f / l_r[r];
#pragma unroll
    for (int jt = 0; jt < 8; jt++)
#pragma unroll
        for (int r = 0; r < 4; r++) {
            size_t idx = ((size_t)b * SEQ + qt * 64 + wave * 16 + lq * 4 + r) * D_MODEL + h * D_HEAD + jt * 16 + lr;
            att[idx] = __float2bfloat16(O[jt][r] * inv[r]);
        }
}

// ---------------- bf16 MFMA GEMM with global_load_lds staging ----------------
#define BM 128
#define BN 128
#define BK 32

template <int EPI>
__global__ __launch_bounds__(256) void gemm_bt(const bf16* __restrict__ A,
                                               const bf16* __restrict__ W,
                                               const float* __restrict__ bias,
                                               const float* __restrict__ res,
                                               float* __restrict__ outF,
                                               bf16* __restrict__ outB,
                                               int M, int N, int K) {
    __shared__ __align__(16) bf16 As[BM * BK];
    __shared__ __align__(16) bf16 Bs[BN * BK];
    int t = threadIdx.x;
    int wave = t >> 6, lane = t & 63;
    int wm = (wave >> 1) * 64;
    int wn = (wave & 1) * 64;
    int lr = lane & 15;
    int lq = lane >> 4;
    int row0 = blockIdx.y * BM;
    int col0 = blockIdx.x * BN;
    int lr4 = lane >> 2;          // 0..15: row within 16-row chunk
    int lc8 = (lane & 3) * 8;     // col elem offset (8 bf16 = 16B)

    v4f acc[4][4] = {};

    for (int k0 = 0; k0 < K; k0 += BK) {
#pragma unroll
        for (int u = 0; u < 2; u++) {
            int c = wave * 2 + u;  // chunk 0..7 (16 rows x 32 cols = 1KB)
            const bf16* ga = A + (size_t)(row0 + c * 16 + lr4) * K + k0 + lc8;
            __builtin_amdgcn_global_load_lds(
                (const __attribute__((address_space(1))) void*)ga,
                (__attribute__((address_space(3))) void*)&As[c * 512], 16, 0, 0);
            const bf16* gb = W + (size_t)(col0 + c * 16 + lr4) * K + k0 + lc8;
            __builtin_amdgcn_global_load_lds(
                (const __attribute__((address_space(1))) void*)gb,
                (__attribute__((address_space(3))) void*)&Bs[c * 512], 16, 0, 0);
        }
        __syncthreads();
        v8bf af[4], bfr[4];
#pragma unroll
        for (int i = 0; i < 4; i++) {
            af[i]  = *(const v8bf*)(&As[(wm + i * 16 + lr) * BK + lq * 8]);
            bfr[i] = *(const v8bf*)(&Bs[(wn + i * 16 + lr) * BK + lq * 8]);
        }
#pragma unroll
        for (int i = 0; i < 4; i++)
#pragma unroll
            for (int j = 0; j < 4; j++)
                acc[i][j] = __builtin_amdgcn_mfma_f32_16x16x32_bf16(af[i], bfr[j], acc[i][j], 0, 0, 0);
        __syncthreads();
    }

#pragma unroll
    for (int i = 0; i < 4; i++) {
#pragma unroll
        for (int j = 0; j < 4; j++) {
#pragma unroll
            for (int r = 0; r < 4; r++) {
                int grow = row0 + wm + i * 16 + lq * 4 + r;
                int gcol = col0 + wn + j * 16 + lr;
                float c = acc[i][j][r];
                size_t idx = (size_t)grow * N + gcol;
                if (EPI == 0) {
                    outF[idx] = c;
                } else if (EPI == 1) {
                    outF[idx] = c + bias[gcol] + res[idx];
                } else {
                    c += bias[gcol];
                    float gel = 0.5f * c * (1.0f + erff(c * 0.7071067811865475f));
                    outB[idx] = __float2bfloat16(gel);
                }
            }
        }
    }
}

extern "C" void kernel_launch(void* const* d_in, const int* in_sizes, int n_in,
                              void* d_out, int out_size, void* d_ws, size_t ws_size,
                              hipStream_t stream) {
    const float* x      = (const float*)d_in[0];
    const float* w_qkv  = (const float*)d_in[1];
    const float* w_proj = (const float*)d_in[2];
    const float* b_proj = (const float*)d_in[3];
    const float* w_ff1  = (const float*)d_in[4];
    const float* b_ff1  = (const float*)d_in[5];
    const float* w_ff2  = (const float*)d_in[6];
    const float* b_ff2  = (const float*)d_in[7];
    const float* g1     = (const float*)d_in[8];
    const float* be1    = (const float*)d_in[9];
    const float* g2     = (const float*)d_in[10];
    const float* be2    = (const float*)d_in[11];
    float* out = (float*)d_out;

    char* ws = (char*)d_ws;
    size_t off = 0;
    auto alloc = [&](size_t bytes) {
        void* p = ws + off;
        off += (bytes + 255) & ~(size_t)255;
        return p;
    };
    bf16*  wqkv_b  = (bf16*)alloc((size_t)3 * D_MODEL * D_MODEL * sizeof(bf16));
    bf16*  wproj_b = (bf16*)alloc((size_t)D_MODEL * D_MODEL * sizeof(bf16));
    bf16*  wff1_b  = (bf16*)alloc((size_t)FFDIM * D_MODEL * sizeof(bf16));
    bf16*  wff2_b  = (bf16*)alloc((size_t)D_MODEL * FFDIM * sizeof(bf16));
    float* qkv_f   = (float*)alloc((size_t)TOKENS * 3 * D_MODEL * sizeof(float));
    bf16*  act_b   = (bf16*)alloc((size_t)TOKENS * D_MODEL * sizeof(bf16));
    float* x2_f    = (float*)alloc((size_t)TOKENS * D_MODEL * sizeof(float));
    bf16*  ff1_b   = (bf16*)qkv_f;   // overlay: qkv dead after attention
    bf16*  vt_g    = (bf16*)x2_f;    // overlay: Vt dead before proj writes x2 (stream-ordered)

    cast_kernel<<<(3 * D_MODEL * D_MODEL / 4 + 255) / 256, 256, 0, stream>>>(w_qkv, wqkv_b, 3 * D_MODEL * D_MODEL / 4);
    cast_kernel<<<(D_MODEL * D_MODEL / 4 + 255) / 256, 256, 0, stream>>>(w_proj, wproj_b, D_MODEL * D_MODEL / 4);
    cast_kernel<<<(FFDIM * D_MODEL / 4 + 255) / 256, 256, 0, stream>>>(w_ff1, wff1_b, FFDIM * D_MODEL / 4);
    cast_kernel<<<(D_MODEL * FFDIM / 4 + 255) / 256, 256, 0, stream>>>(w_ff2, wff2_b, D_MODEL * FFDIM / 4);

    ln_kernel<<<TOKENS, 256, 0, stream>>>(x, g1, be1, act_b);

    gemm_bt<0><<<dim3(3 * D_MODEL / BN, TOKENS / BM), 256, 0, stream>>>(
        act_b, wqkv_b, nullptr, nullptr, qkv_f, nullptr, TOKENS, 3 * D_MODEL, D_MODEL);

    rope_kernel<<<TOKENS * N_HEADS / 4, 256, 0, stream>>>(qkv_f);

    vt_kernel<<<dim3(BATCH * N_HEADS, SEQ / 64, D_HEAD / 32), 256, 0, stream>>>(qkv_f, vt_g);

    flash_attn<<<dim3(BATCH * N_HEADS, SEQ / 64), 256, 0, stream>>>(qkv_f, vt_g, act_b);

    gemm_bt<1><<<dim3(D_MODEL / BN, TOKENS / BM), 256, 0, stream>>>(
        act_b, wproj_b, b_proj, x, x2_f, nullptr, TOKENS, D_MODEL, D_MODEL);

    ln_kernel<<<TOKENS, 256, 0, stream>>>(x2_f, g2, be2, act_b);

    gemm_bt<2><<<dim3(FFDIM / BN, TOKENS / BM), 256, 0, stream>>>(
        act_b, wff1_b, b_ff1, nullptr, nullptr, ff1_b, TOKENS, FFDIM, D_MODEL);

    gemm_bt<1><<<dim3(D_MODEL / BN, TOKENS / BM), 256, 0, stream>>>(
        ff1_b, wff2_b, b_ff2, x2_f, out, nullptr, TOKENS, D_MODEL, FFDIM);

    (void)in_sizes; (void)n_in; (void)out_size; (void)ws_size;
}

// Round 3
// 1042.348 us; speedup vs baseline: 8.7037x; 1.0632x over previous
//
#include <hip/hip_runtime.h>
#include <hip/hip_bf16.h>
#include <cmath>

#define D_MODEL 2048
#define N_HEADS 16
#define D_HEAD  128
#define FFDIM   8192
#define BATCH   2
#define SEQ     2048
#define TOKENS  (BATCH * SEQ)

using bf16 = __hip_bfloat16;
typedef __bf16 v8bf __attribute__((ext_vector_type(8)));
typedef float  v4f  __attribute__((ext_vector_type(4)));

// ---------------- weight cast f32 -> bf16 ----------------
__global__ __launch_bounds__(256) void cast_kernel(const float* __restrict__ in,
                                                   bf16* __restrict__ out, int n4) {
    int i = blockIdx.x * 256 + threadIdx.x;
    if (i < n4) {
        float4 f = ((const float4*)in)[i];
        int o = i * 4;
        out[o + 0] = __float2bfloat16(f.x);
        out[o + 1] = __float2bfloat16(f.y);
        out[o + 2] = __float2bfloat16(f.z);
        out[o + 3] = __float2bfloat16(f.w);
    }
}

// ---------------- LayerNorm (one row per block), fp32 in -> bf16 out ----------------
__global__ __launch_bounds__(256) void ln_kernel(const float* __restrict__ x,
                                                 const float* __restrict__ g,
                                                 const float* __restrict__ b,
                                                 bf16* __restrict__ out) {
    int row = blockIdx.x;
    int t = threadIdx.x;
    const float* xr = x + (size_t)row * D_MODEL;
    float v[8];
    float s = 0.f, s2 = 0.f;
#pragma unroll
    for (int i = 0; i < 8; i++) {
        float val = xr[t + 256 * i];
        v[i] = val;
        s += val;
        s2 += val * val;
    }
#pragma unroll
    for (int off = 32; off > 0; off >>= 1) {
        s  += __shfl_down(s, off, 64);
        s2 += __shfl_down(s2, off, 64);
    }
    __shared__ float ws1[4], ws2[4];
    int wv = t >> 6;
    if ((t & 63) == 0) { ws1[wv] = s; ws2[wv] = s2; }
    __syncthreads();
    float fs  = ws1[0] + ws1[1] + ws1[2] + ws1[3];
    float fs2 = ws2[0] + ws2[1] + ws2[2] + ws2[3];
    float mean = fs * (1.0f / D_MODEL);
    float var  = fs2 * (1.0f / D_MODEL) - mean * mean;
    float rstd = rsqrtf(var + 1e-5f);
    bf16* orow = out + (size_t)row * D_MODEL;
#pragma unroll
    for (int i = 0; i < 8; i++) {
        int c = t + 256 * i;
        orow[c] = __float2bfloat16((v[i] - mean) * rstd * g[c] + b[c]);
    }
}

// ---------------- RoPE in-place on bf16 qkv; folds 1/sqrt(d) into q ----------------
__global__ __launch_bounds__(256) void rope_kernel(bf16* __restrict__ qkv) {
    int unit = blockIdx.x * 4 + (threadIdx.x >> 6);
    int j = threadIdx.x & 63;
    int h = unit & (N_HEADS - 1);
    int tok = unit >> 4;
    int pos = tok & (SEQ - 1);
    float invf = powf(10000.0f, -(float)j / 64.0f);
    float ang = (float)pos * invf;
    float c = cosf(ang), s = sinf(ang);
    const float sc = 0.08838834764831845f; // 1/sqrt(128), folded into q
    size_t base = (size_t)tok * (3 * D_MODEL) + h * D_HEAD;
    float q1 = __bfloat162float(qkv[base + j]), q2 = __bfloat162float(qkv[base + j + 64]);
    qkv[base + j]      = __float2bfloat16((q1 * c - q2 * s) * sc);
    qkv[base + j + 64] = __float2bfloat16((q2 * c + q1 * s) * sc);
    size_t kb = base + D_MODEL;
    float k1 = __bfloat162float(qkv[kb + j]), k2 = __bfloat162float(qkv[kb + j + 64]);
    qkv[kb + j]      = __float2bfloat16(k1 * c - k2 * s);
    qkv[kb + j + 64] = __float2bfloat16(k2 * c + k1 * s);
}

// ---------------- V transpose: qkv bf16 [tok][3D] -> Vt bf16 [bh][d][k] ----------------
__global__ __launch_bounds__(256) void vt_kernel(const bf16* __restrict__ qkv,
                                                 bf16* __restrict__ vt) {
    __shared__ float tile[32][65];
    int bh = blockIdx.x;
    int k0 = blockIdx.y * 64;
    int d0 = blockIdx.z * 32;
    int b = bh >> 4, h = bh & 15;
    int t = threadIdx.x;
    const bf16* src = qkv + ((size_t)b * SEQ + k0) * (3 * D_MODEL) + 2 * D_MODEL + h * D_HEAD + d0;
#pragma unroll
    for (int i = 0; i < 8; i++) {
        int e = t + 256 * i;
        int kr = e >> 5, dc = e & 31;
        tile[dc][kr] = __bfloat162float(src[(size_t)kr * (3 * D_MODEL) + dc]);
    }
    __syncthreads();
    bf16* dst = vt + ((size_t)bh * D_HEAD + d0) * SEQ + k0;
#pragma unroll
    for (int i = 0; i < 8; i++) {
        int e = t + 256 * i;
        int dr = e >> 6, kc = e & 63;
        dst[(size_t)dr * SEQ + kc] = __float2bfloat16(tile[dr][kc]);
    }
}

// ---------------- flash attention: MFMA, online softmax, bf16 qkv ----------------
#define KS_STRIDE 136
#define VT_STRIDE 72
#define PS_STRIDE 72

__global__ __launch_bounds__(256) void flash_attn(const bf16* __restrict__ qkv,
                                                  const bf16* __restrict__ vt,
                                                  bf16* __restrict__ att) {
    __shared__ __align__(16) bf16 Ks[64 * KS_STRIDE];       // [kpos][d] padded
    __shared__ __align__(16) bf16 Vts[D_HEAD * VT_STRIDE];  // [d][kpos] padded
    __shared__ __align__(16) bf16 Ps[4 * 16 * PS_STRIDE];   // per-wave [q][kpos]

    int bh = blockIdx.x;
    int qt = (int)gridDim.y - 1 - (int)blockIdx.y;  // heavy q-tiles first
    int b = bh >> 4, h = bh & 15;
    int t = threadIdx.x, wave = t >> 6, lane = t & 63;
    int lr = lane & 15, lq = lane >> 4;

    // Q fragments (scale already folded in by rope)
    const bf16* qp = qkv + ((size_t)b * SEQ + qt * 64 + wave * 16 + lr) * (3 * D_MODEL) + h * D_HEAD;
    v8bf aq[4];
#pragma unroll
    for (int c = 0; c < 4; c++)
        aq[c] = *(const v8bf*)(qp + c * 32 + lq * 8);

    float m_r[4], l_r[4];
    v4f O[8] = {};
#pragma unroll
    for (int r = 0; r < 4; r++) { m_r[r] = -1e30f; l_r[r] = 0.f; }

    int n_tiles = qt + 1;
    for (int kt = 0; kt < n_tiles; kt++) {
        int kv0 = kt * 64;
        __syncthreads();
        // stage K tile 64x128 (bf16 copy, 16B chunks)
        {
            const bf16* kbase = qkv + ((size_t)b * SEQ + kv0) * (3 * D_MODEL) + D_MODEL + h * D_HEAD;
#pragma unroll
            for (int i = 0; i < 4; i++) {
                int e = t + 256 * i;
                int kr = e >> 4, c8 = (e & 15) * 8;
                *(uint4*)&Ks[kr * KS_STRIDE + c8] = *(const uint4*)(kbase + (size_t)kr * (3 * D_MODEL) + c8);
            }
            // stage Vt tile 128x64 (bf16 copy)
            const bf16* vbase = vt + (size_t)bh * D_HEAD * SEQ + kv0;
#pragma unroll
            for (int i = 0; i < 4; i++) {
                int e8 = t + 256 * i;
                int dr = e8 >> 3, k8 = (e8 & 7) * 8;
                *(uint4*)&Vts[dr * VT_STRIDE + k8] = *(const uint4*)(vbase + (size_t)dr * SEQ + k8);
            }
        }
        __syncthreads();

        // scores S = Q K^T (scale pre-folded)
        v4f sc[4];
#pragma unroll
        for (int nt = 0; nt < 4; nt++) {
            v4f a = {};
#pragma unroll
            for (int c = 0; c < 4; c++) {
                v8bf bk = *(const v8bf*)&Ks[(nt * 16 + lr) * KS_STRIDE + c * 32 + lq * 8];
                a = __builtin_amdgcn_mfma_f32_16x16x32_bf16(aq[c], bk, a, 0, 0, 0);
            }
            sc[nt] = a;
        }
        // causal mask on diagonal tile
        if (kt == n_tiles - 1) {
#pragma unroll
            for (int nt = 0; nt < 4; nt++)
#pragma unroll
                for (int r = 0; r < 4; r++) {
                    int cl = nt * 16 + lr, rl = wave * 16 + lq * 4 + r;
                    if (cl > rl) sc[nt][r] = -1e30f;
                }
        }
        // online softmax
        float mt[4];
#pragma unroll
        for (int r = 0; r < 4; r++) {
            float v = fmaxf(fmaxf(sc[0][r], sc[1][r]), fmaxf(sc[2][r], sc[3][r]));
#pragma unroll
            for (int mk = 8; mk >= 1; mk >>= 1) v = fmaxf(v, __shfl_xor(v, mk, 64));
            mt[r] = v;
        }
        float alpha[4];
#pragma unroll
        for (int r = 0; r < 4; r++) {
            float mn = fmaxf(m_r[r], mt[r]);
            alpha[r] = __expf(m_r[r] - mn);
            m_r[r] = mn;
        }
        bf16* pw = &Ps[wave * 16 * PS_STRIDE];
        float rs[4] = {0.f, 0.f, 0.f, 0.f};
#pragma unroll
        for (int nt = 0; nt < 4; nt++)
#pragma unroll
            for (int r = 0; r < 4; r++) {
                float p = __expf(sc[nt][r] - m_r[r]);
                rs[r] += p;
                pw[(lq * 4 + r) * PS_STRIDE + nt * 16 + lr] = __float2bfloat16(p);
            }
#pragma unroll
        for (int r = 0; r < 4; r++) {
            float v = rs[r];
#pragma unroll
            for (int mk = 8; mk >= 1; mk >>= 1) v += __shfl_xor(v, mk, 64);
            l_r[r] = l_r[r] * alpha[r] + v;
        }
#pragma unroll
        for (int jt = 0; jt < 8; jt++)
#pragma unroll
            for (int r = 0; r < 4; r++) O[jt][r] *= alpha[r];

        // wave-private P writes must complete before cross-lane frag reads
        asm volatile("s_waitcnt lgkmcnt(0)" ::: "memory");

        v8bf ap[2];
#pragma unroll
        for (int c = 0; c < 2; c++)
            ap[c] = *(const v8bf*)&pw[lr * PS_STRIDE + c * 32 + lq * 8];
#pragma unroll
        for (int jt = 0; jt < 8; jt++) {
#pragma unroll
            for (int c = 0; c < 2; c++) {
                v8bf bv = *(const v8bf*)&Vts[(jt * 16 + lr) * VT_STRIDE + c * 32 + lq * 8];
                O[jt] = __builtin_amdgcn_mfma_f32_16x16x32_bf16(ap[c], bv, O[jt], 0, 0, 0);
            }
        }
    }

    float inv[4];
#pragma unroll
    for (int r = 0; r < 4; r++) inv[r] = 1.0f / l_r[r];
#pragma unroll
    for (int jt = 0; jt < 8; jt++)
#pragma unroll
        for (int r = 0; r < 4; r++) {
            size_t idx = ((size_t)b * SEQ + qt * 64 + wave * 16 + lq * 4 + r) * D_MODEL + h * D_HEAD + jt * 16 + lr;
            att[idx] = __float2bfloat16(O[jt][r] * inv[r]);
        }
}

// ---------------- bf16 MFMA GEMM, global_load_lds staging, XCD/L2 swizzle ----------------
// EPI 0: fp32 out | 1: +bias+residual fp32 | 2: +bias,GELU bf16 | 3: plain bf16
#define BM 128
#define BN 128
#define BK 32

template <int EPI>
__global__ __launch_bounds__(256) void gemm_bt(const bf16* __restrict__ A,
                                               const bf16* __restrict__ W,
                                               const float* __restrict__ bias,
                                               const float* __restrict__ res,
                                               float* __restrict__ outF,
                                               bf16* __restrict__ outB,
                                               int M, int N, int K) {
    __shared__ __align__(16) bf16 As[BM * BK];
    __shared__ __align__(16) bf16 Bs[BN * BK];
    int t = threadIdx.x;
    int wave = t >> 6, lane = t & 63;
    int wm = (wave >> 1) * 64;
    int wn = (wave & 1) * 64;
    int lr = lane & 15;
    int lq = lane >> 4;

    // ---- block swizzle: XCD-contiguous remap, then 8-M-tile panel, column-major ----
    // (grid sizes here are all multiples of 8 in total blocks and nby==32)
    int nbx = gridDim.x;
    int bid = (int)blockIdx.y * nbx + (int)blockIdx.x;
    int per = (nbx * (int)gridDim.y) >> 3;
    int lbid = (bid & 7) * per + (bid >> 3);   // XCD k gets contiguous logical ids
    const int GM = 8;
    int pw = GM * nbx;
    int panel = lbid / pw;
    int rem = lbid - panel * pw;
    int bm = panel * GM + (rem & (GM - 1));
    int bn = rem >> 3;
    int row0 = bm * BM;
    int col0 = bn * BN;

    int lr4 = lane >> 2;
    int lc8 = (lane & 3) * 8;

    v4f acc[4][4] = {};

    for (int k0 = 0; k0 < K; k0 += BK) {
#pragma unroll
        for (int u = 0; u < 2; u++) {
            int c = wave * 2 + u;
            const bf16* ga = A + (size_t)(row0 + c * 16 + lr4) * K + k0 + lc8;
            __builtin_amdgcn_global_load_lds(
                (const __attribute__((address_space(1))) void*)ga,
                (__attribute__((address_space(3))) void*)&As[c * 512], 16, 0, 0);
            const bf16* gb = W + (size_t)(col0 + c * 16 + lr4) * K + k0 + lc8;
            __builtin_amdgcn_global_load_lds(
                (const __attribute__((address_space(1))) void*)gb,
                (__attribute__((address_space(3))) void*)&Bs[c * 512], 16, 0, 0);
        }
        __syncthreads();
        v8bf af[4], bfr[4];
#pragma unroll
        for (int i = 0; i < 4; i++) {
            af[i]  = *(const v8bf*)(&As[(wm + i * 16 + lr) * BK + lq * 8]);
            bfr[i] = *(const v8bf*)(&Bs[(wn + i * 16 + lr) * BK + lq * 8]);
        }
#pragma unroll
        for (int i = 0; i < 4; i++)
#pragma unroll
            for (int j = 0; j < 4; j++)
                acc[i][j] = __builtin_amdgcn_mfma_f32_16x16x32_bf16(af[i], bfr[j], acc[i][j], 0, 0, 0);
        __syncthreads();
    }

#pragma unroll
    for (int i = 0; i < 4; i++) {
#pragma unroll
        for (int j = 0; j < 4; j++) {
#pragma unroll
            for (int r = 0; r < 4; r++) {
                int grow = row0 + wm + i * 16 + lq * 4 + r;
                int gcol = col0 + wn + j * 16 + lr;
                float c = acc[i][j][r];
                size_t idx = (size_t)grow * N + gcol;
                if (EPI == 0) {
                    outF[idx] = c;
                } else if (EPI == 1) {
                    outF[idx] = c + bias[gcol] + res[idx];
                } else if (EPI == 2) {
                    c += bias[gcol];
                    float gel = 0.5f * c * (1.0f + erff(c * 0.7071067811865475f));
                    outB[idx] = __float2bfloat16(gel);
                } else {
                    outB[idx] = __float2bfloat16(c);
                }
            }
        }
    }
}

extern "C" void kernel_launch(void* const* d_in, const int* in_sizes, int n_in,
                              void* d_out, int out_size, void* d_ws, size_t ws_size,
                              hipStream_t stream) {
    const float* x      = (const float*)d_in[0];
    const float* w_qkv  = (const float*)d_in[1];
    const float* w_proj = (const float*)d_in[2];
    const float* b_proj = (const float*)d_in[3];
    const float* w_ff1  = (const float*)d_in[4];
    const float* b_ff1  = (const float*)d_in[5];
    const float* w_ff2  = (const float*)d_in[6];
    const float* b_ff2  = (const float*)d_in[7];
    const float* g1     = (const float*)d_in[8];
    const float* be1    = (const float*)d_in[9];
    const float* g2     = (const float*)d_in[10];
    const float* be2    = (const float*)d_in[11];
    float* out = (float*)d_out;

    char* ws = (char*)d_ws;
    size_t off = 0;
    auto alloc = [&](size_t bytes) {
        void* p = ws + off;
        off += (bytes + 255) & ~(size_t)255;
        return p;
    };
    bf16*  wqkv_b  = (bf16*)alloc((size_t)3 * D_MODEL * D_MODEL * sizeof(bf16));
    bf16*  wproj_b = (bf16*)alloc((size_t)D_MODEL * D_MODEL * sizeof(bf16));
    bf16*  wff1_b  = (bf16*)alloc((size_t)FFDIM * D_MODEL * sizeof(bf16));
    bf16*  wff2_b  = (bf16*)alloc((size_t)D_MODEL * FFDIM * sizeof(bf16));
    // shared region: qkv (bf16, 50MB) then ff1 activations (bf16, 67MB)
    bf16*  qkv_b   = (bf16*)alloc((size_t)TOKENS * FFDIM * sizeof(bf16));
    bf16*  ff1_b   = qkv_b;
    bf16*  act_b   = (bf16*)alloc((size_t)TOKENS * D_MODEL * sizeof(bf16));
    float* x2_f    = (float*)alloc((size_t)TOKENS * D_MODEL * sizeof(float));
    bf16*  vt_g    = (bf16*)x2_f;    // overlay: Vt dead before proj writes x2 (stream-ordered)

    cast_kernel<<<(3 * D_MODEL * D_MODEL / 4 + 255) / 256, 256, 0, stream>>>(w_qkv, wqkv_b, 3 * D_MODEL * D_MODEL / 4);
    cast_kernel<<<(D_MODEL * D_MODEL / 4 + 255) / 256, 256, 0, stream>>>(w_proj, wproj_b, D_MODEL * D_MODEL / 4);
    cast_kernel<<<(FFDIM * D_MODEL / 4 + 255) / 256, 256, 0, stream>>>(w_ff1, wff1_b, FFDIM * D_MODEL / 4);
    cast_kernel<<<(D_MODEL * FFDIM / 4 + 255) / 256, 256, 0, stream>>>(w_ff2, wff2_b, D_MODEL * FFDIM / 4);

    ln_kernel<<<TOKENS, 256, 0, stream>>>(x, g1, be1, act_b);

    // QKV GEMM -> bf16
    gemm_bt<3><<<dim3(3 * D_MODEL / BN, TOKENS / BM), 256, 0, stream>>>(
        act_b, wqkv_b, nullptr, nullptr, nullptr, qkv_b, TOKENS, 3 * D_MODEL, D_MODEL);

    rope_kernel<<<TOKENS * N_HEADS / 4, 256, 0, stream>>>(qkv_b);

    vt_kernel<<<dim3(BATCH * N_HEADS, SEQ / 64, D_HEAD / 32), 256, 0, stream>>>(qkv_b, vt_g);

    flash_attn<<<dim3(BATCH * N_HEADS, SEQ / 64), 256, 0, stream>>>(qkv_b, vt_g, act_b);

    gemm_bt<1><<<dim3(D_MODEL / BN, TOKENS / BM), 256, 0, stream>>>(
        act_b, wproj_b, b_proj, x, x2_f, nullptr, TOKENS, D_MODEL, D_MODEL);

    ln_kernel<<<TOKENS, 256, 0, stream>>>(x2_f, g2, be2, act_b);

    gemm_bt<2><<<dim3(FFDIM / BN, TOKENS / BM), 256, 0, stream>>>(
        act_b, wff1_b, b_ff1, nullptr, nullptr, ff1_b, TOKENS, FFDIM, D_MODEL);

    gemm_bt<1><<<dim3(D_MODEL / BN, TOKENS / BM), 256, 0, stream>>>(
        ff1_b, wff2_b, b_ff2, x2_f, out, nullptr, TOKENS, D_MODEL, FFDIM);

    (void)in_sizes; (void)n_in; (void)out_size; (void)ws_size;
}

// Round 4
// 922.021 us; speedup vs baseline: 9.8396x; 1.1305x over previous
//
#include <hip/hip_runtime.h>
#include <hip/hip_bf16.h>
#include <cmath>

#define D_MODEL 2048
#define N_HEADS 16
#define D_HEAD  128
#define FFDIM   8192
#define BATCH   2
#define SEQ     2048
#define TOKENS  (BATCH * SEQ)

using bf16 = __hip_bfloat16;
typedef __bf16 v8bf __attribute__((ext_vector_type(8)));
typedef float  v4f  __attribute__((ext_vector_type(4)));

// ---------------- fused weight cast f32 -> bf16 (all 4 weight mats) ----------------
#define N0 (3 * D_MODEL * D_MODEL / 4)
#define N1 (D_MODEL * D_MODEL / 4)
#define N2 (FFDIM * D_MODEL / 4)
#define N3 (D_MODEL * FFDIM / 4)

__global__ __launch_bounds__(256) void cast4_kernel(const float* __restrict__ w0,
                                                    const float* __restrict__ w1,
                                                    const float* __restrict__ w2,
                                                    const float* __restrict__ w3,
                                                    bf16* __restrict__ o0,
                                                    bf16* __restrict__ o1,
                                                    bf16* __restrict__ o2,
                                                    bf16* __restrict__ o3) {
    int i = blockIdx.x * 256 + threadIdx.x;
    const float* src; bf16* dst; int j;
    if (i < N0)                { src = w0; dst = o0; j = i; }
    else if (i < N0 + N1)      { src = w1; dst = o1; j = i - N0; }
    else if (i < N0 + N1 + N2) { src = w2; dst = o2; j = i - N0 - N1; }
    else                       { src = w3; dst = o3; j = i - N0 - N1 - N2; }
    float4 f = ((const float4*)src)[j];
    int o = j * 4;
    dst[o + 0] = __float2bfloat16(f.x);
    dst[o + 1] = __float2bfloat16(f.y);
    dst[o + 2] = __float2bfloat16(f.z);
    dst[o + 3] = __float2bfloat16(f.w);
}

// ---------------- LayerNorm (one row per block), fp32 in -> bf16 out ----------------
__global__ __launch_bounds__(256) void ln_kernel(const float* __restrict__ x,
                                                 const float* __restrict__ g,
                                                 const float* __restrict__ b,
                                                 bf16* __restrict__ out) {
    int row = blockIdx.x;
    int t = threadIdx.x;
    const float* xr = x + (size_t)row * D_MODEL;
    float v[8];
    float s = 0.f, s2 = 0.f;
#pragma unroll
    for (int i = 0; i < 8; i++) {
        float val = xr[t + 256 * i];
        v[i] = val;
        s += val;
        s2 += val * val;
    }
#pragma unroll
    for (int off = 32; off > 0; off >>= 1) {
        s  += __shfl_down(s, off, 64);
        s2 += __shfl_down(s2, off, 64);
    }
    __shared__ float ws1[4], ws2[4];
    int wv = t >> 6;
    if ((t & 63) == 0) { ws1[wv] = s; ws2[wv] = s2; }
    __syncthreads();
    float fs  = ws1[0] + ws1[1] + ws1[2] + ws1[3];
    float fs2 = ws2[0] + ws2[1] + ws2[2] + ws2[3];
    float mean = fs * (1.0f / D_MODEL);
    float var  = fs2 * (1.0f / D_MODEL) - mean * mean;
    float rstd = rsqrtf(var + 1e-5f);
    bf16* orow = out + (size_t)row * D_MODEL;
#pragma unroll
    for (int i = 0; i < 8; i++) {
        int c = t + 256 * i;
        orow[c] = __float2bfloat16((v[i] - mean) * rstd * g[c] + b[c]);
    }
}

// ---------------- RoPE in-place on bf16 qkv; folds 1/sqrt(d) into q ----------------
__global__ __launch_bounds__(256) void rope_kernel(bf16* __restrict__ qkv) {
    int unit = blockIdx.x * 4 + (threadIdx.x >> 6);
    int j = threadIdx.x & 63;
    int h = unit & (N_HEADS - 1);
    int tok = unit >> 4;
    int pos = tok & (SEQ - 1);
    float invf = powf(10000.0f, -(float)j / 64.0f);
    float ang = (float)pos * invf;
    float c = cosf(ang), s = sinf(ang);
    const float sc = 0.08838834764831845f; // 1/sqrt(128), folded into q
    size_t base = (size_t)tok * (3 * D_MODEL) + h * D_HEAD;
    float q1 = __bfloat162float(qkv[base + j]), q2 = __bfloat162float(qkv[base + j + 64]);
    qkv[base + j]      = __float2bfloat16((q1 * c - q2 * s) * sc);
    qkv[base + j + 64] = __float2bfloat16((q2 * c + q1 * s) * sc);
    size_t kb = base + D_MODEL;
    float k1 = __bfloat162float(qkv[kb + j]), k2 = __bfloat162float(qkv[kb + j + 64]);
    qkv[kb + j]      = __float2bfloat16(k1 * c - k2 * s);
    qkv[kb + j + 64] = __float2bfloat16(k2 * c + k1 * s);
}

// ---------------- V transpose: qkv bf16 [tok][3D] -> Vt bf16 [bh][d][k] ----------------
__global__ __launch_bounds__(256) void vt_kernel(const bf16* __restrict__ qkv,
                                                 bf16* __restrict__ vt) {
    __shared__ float tile[32][65];
    int bh = blockIdx.x;
    int k0 = blockIdx.y * 64;
    int d0 = blockIdx.z * 32;
    int b = bh >> 4, h = bh & 15;
    int t = threadIdx.x;
    const bf16* src = qkv + ((size_t)b * SEQ + k0) * (3 * D_MODEL) + 2 * D_MODEL + h * D_HEAD + d0;
#pragma unroll
    for (int i = 0; i < 8; i++) {
        int e = t + 256 * i;
        int kr = e >> 5, dc = e & 31;
        tile[dc][kr] = __bfloat162float(src[(size_t)kr * (3 * D_MODEL) + dc]);
    }
    __syncthreads();
    bf16* dst = vt + ((size_t)bh * D_HEAD + d0) * SEQ + k0;
#pragma unroll
    for (int i = 0; i < 8; i++) {
        int e = t + 256 * i;
        int dr = e >> 6, kc = e & 63;
        dst[(size_t)dr * SEQ + kc] = __float2bfloat16(tile[dr][kc]);
    }
}

// ---------------- flash attention: MFMA, online softmax, bf16 qkv ----------------
#define KS_STRIDE 136
#define VT_STRIDE 72
#define PS_STRIDE 72

__global__ __launch_bounds__(256) void flash_attn(const bf16* __restrict__ qkv,
                                                  const bf16* __restrict__ vt,
                                                  bf16* __restrict__ att) {
    __shared__ __align__(16) bf16 Ks[64 * KS_STRIDE];       // [kpos][d] padded
    __shared__ __align__(16) bf16 Vts[D_HEAD * VT_STRIDE];  // [d][kpos] padded
    __shared__ __align__(16) bf16 Ps[4 * 16 * PS_STRIDE];   // per-wave [q][kpos]

    int bh = blockIdx.x;
    int qt = (int)gridDim.y - 1 - (int)blockIdx.y;  // heavy q-tiles first
    int b = bh >> 4, h = bh & 15;
    int t = threadIdx.x, wave = t >> 6, lane = t & 63;
    int lr = lane & 15, lq = lane >> 4;

    // Q fragments (scale already folded in by rope)
    const bf16* qp = qkv + ((size_t)b * SEQ + qt * 64 + wave * 16 + lr) * (3 * D_MODEL) + h * D_HEAD;
    v8bf aq[4];
#pragma unroll
    for (int c = 0; c < 4; c++)
        aq[c] = *(const v8bf*)(qp + c * 32 + lq * 8);

    float m_r[4], l_r[4];
    v4f O[8] = {};
#pragma unroll
    for (int r = 0; r < 4; r++) { m_r[r] = -1e30f; l_r[r] = 0.f; }

    int n_tiles = qt + 1;
    for (int kt = 0; kt < n_tiles; kt++) {
        int kv0 = kt * 64;
        __syncthreads();
        {
            const bf16* kbase = qkv + ((size_t)b * SEQ + kv0) * (3 * D_MODEL) + D_MODEL + h * D_HEAD;
#pragma unroll
            for (int i = 0; i < 4; i++) {
                int e = t + 256 * i;
                int kr = e >> 4, c8 = (e & 15) * 8;
                *(uint4*)&Ks[kr * KS_STRIDE + c8] = *(const uint4*)(kbase + (size_t)kr * (3 * D_MODEL) + c8);
            }
            const bf16* vbase = vt + (size_t)bh * D_HEAD * SEQ + kv0;
#pragma unroll
            for (int i = 0; i < 4; i++) {
                int e8 = t + 256 * i;
                int dr = e8 >> 3, k8 = (e8 & 7) * 8;
                *(uint4*)&Vts[dr * VT_STRIDE + k8] = *(const uint4*)(vbase + (size_t)dr * SEQ + k8);
            }
        }
        __syncthreads();

        v4f sc[4];
#pragma unroll
        for (int nt = 0; nt < 4; nt++) {
            v4f a = {};
#pragma unroll
            for (int c = 0; c < 4; c++) {
                v8bf bk = *(const v8bf*)&Ks[(nt * 16 + lr) * KS_STRIDE + c * 32 + lq * 8];
                a = __builtin_amdgcn_mfma_f32_16x16x32_bf16(aq[c], bk, a, 0, 0, 0);
            }
            sc[nt] = a;
        }
        if (kt == n_tiles - 1) {
#pragma unroll
            for (int nt = 0; nt < 4; nt++)
#pragma unroll
                for (int r = 0; r < 4; r++) {
                    int cl = nt * 16 + lr, rl = wave * 16 + lq * 4 + r;
                    if (cl > rl) sc[nt][r] = -1e30f;
                }
        }
        float mt[4];
#pragma unroll
        for (int r = 0; r < 4; r++) {
            float v = fmaxf(fmaxf(sc[0][r], sc[1][r]), fmaxf(sc[2][r], sc[3][r]));
#pragma unroll
            for (int mk = 8; mk >= 1; mk >>= 1) v = fmaxf(v, __shfl_xor(v, mk, 64));
            mt[r] = v;
        }
        float alpha[4];
#pragma unroll
        for (int r = 0; r < 4; r++) {
            float mn = fmaxf(m_r[r], mt[r]);
            alpha[r] = __expf(m_r[r] - mn);
            m_r[r] = mn;
        }
        bf16* pw = &Ps[wave * 16 * PS_STRIDE];
        float rs[4] = {0.f, 0.f, 0.f, 0.f};
#pragma unroll
        for (int nt = 0; nt < 4; nt++)
#pragma unroll
            for (int r = 0; r < 4; r++) {
                float p = __expf(sc[nt][r] - m_r[r]);
                rs[r] += p;
                pw[(lq * 4 + r) * PS_STRIDE + nt * 16 + lr] = __float2bfloat16(p);
            }
#pragma unroll
        for (int r = 0; r < 4; r++) {
            float v = rs[r];
#pragma unroll
            for (int mk = 8; mk >= 1; mk >>= 1) v += __shfl_xor(v, mk, 64);
            l_r[r] = l_r[r] * alpha[r] + v;
        }
#pragma unroll
        for (int jt = 0; jt < 8; jt++)
#pragma unroll
            for (int r = 0; r < 4; r++) O[jt][r] *= alpha[r];

        asm volatile("s_waitcnt lgkmcnt(0)" ::: "memory");

        v8bf ap[2];
#pragma unroll
        for (int c = 0; c < 2; c++)
            ap[c] = *(const v8bf*)&pw[lr * PS_STRIDE + c * 32 + lq * 8];
#pragma unroll
        for (int jt = 0; jt < 8; jt++) {
#pragma unroll
            for (int c = 0; c < 2; c++) {
                v8bf bv = *(const v8bf*)&Vts[(jt * 16 + lr) * VT_STRIDE + c * 32 + lq * 8];
                O[jt] = __builtin_amdgcn_mfma_f32_16x16x32_bf16(ap[c], bv, O[jt], 0, 0, 0);
            }
        }
    }

    float inv[4];
#pragma unroll
    for (int r = 0; r < 4; r++) inv[r] = 1.0f / l_r[r];
#pragma unroll
    for (int jt = 0; jt < 8; jt++)
#pragma unroll
        for (int r = 0; r < 4; r++) {
            size_t idx = ((size_t)b * SEQ + qt * 64 + wave * 16 + lq * 4 + r) * D_MODEL + h * D_HEAD + jt * 16 + lr;
            att[idx] = __float2bfloat16(O[jt][r] * inv[r]);
        }
}

// ---------------- bf16 MFMA GEMM: BK=64, XOR-swizzled LDS, glb->LDS DMA, XCD swizzle ----
// EPI 0: fp32 out | 1: +bias+residual fp32 | 2: +bias,GELU bf16 | 3: plain bf16
#define BM 128
#define BN 128
#define BK 64

template <int EPI>
__global__ __launch_bounds__(256) void gemm_bt(const bf16* __restrict__ A,
                                               const bf16* __restrict__ W,
                                               const float* __restrict__ bias,
                                               const float* __restrict__ res,
                                               float* __restrict__ outF,
                                               bf16* __restrict__ outB,
                                               int M, int N, int K) {
    __shared__ __align__(16) bf16 As[BM * BK];  // 16 KB, row-major stride 64, XOR-swizzled 16B blocks
    __shared__ __align__(16) bf16 Bs[BN * BK];  // 16 KB
    int t = threadIdx.x;
    int wave = t >> 6, lane = t & 63;
    int wm = (wave >> 1) * 64;
    int wn = (wave & 1) * 64;
    int lr = lane & 15;
    int lq = lane >> 4;

    // ---- block swizzle: XCD-contiguous remap, then 8-M-tile panel, column-major ----
    int nbx = gridDim.x;
    int bid = (int)blockIdx.y * nbx + (int)blockIdx.x;
    int per = (nbx * (int)gridDim.y) >> 3;
    int lbid = (bid & 7) * per + (bid >> 3);
    const int GM = 8;
    int pw = GM * nbx;
    int panel = lbid / pw;
    int rem = lbid - panel * pw;
    int bm = panel * GM + (rem & (GM - 1));
    int bn = rem >> 3;
    int row0 = bm * BM;
    int col0 = bn * BN;

    // staging lane geometry: chunk = 8 rows x 64 cols (1KB). lane -> (srow, dest block sb);
    // the GLOBAL k-block fetched is sb ^ srow so LDS block b holds global block b ^ (row&7).
    int srow = lane >> 3;             // 0..7
    int sblk = lane & 7;              // dest 16B block
    int scol = ((sblk ^ srow) * 8);   // source k element offset

    v4f acc[4][4] = {};

    for (int k0 = 0; k0 < K; k0 += BK) {
#pragma unroll
        for (int u = 0; u < 4; u++) {
            int c = wave * 4 + u;     // chunk 0..15
            const bf16* ga = A + (size_t)(row0 + c * 8 + srow) * K + k0 + scol;
            __builtin_amdgcn_global_load_lds(
                (const __attribute__((address_space(1))) void*)ga,
                (__attribute__((address_space(3))) void*)&As[c * 512], 16, 0, 0);
            const bf16* gb = W + (size_t)(col0 + c * 8 + srow) * K + k0 + scol;
            __builtin_amdgcn_global_load_lds(
                (const __attribute__((address_space(1))) void*)gb,
                (__attribute__((address_space(3))) void*)&Bs[c * 512], 16, 0, 0);
        }
        __syncthreads();
#pragma unroll
        for (int half = 0; half < 2; half++) {
            v8bf af[4], bfr[4];
            int gblk = half * 4 + lq;             // global k-block wanted
            int soff = ((gblk ^ (lr & 7)) * 8);   // swizzled LDS element offset
#pragma unroll
            for (int i = 0; i < 4; i++) {
                af[i]  = *(const v8bf*)(&As[(wm + i * 16 + lr) * BK + soff]);
                bfr[i] = *(const v8bf*)(&Bs[(wn + i * 16 + lr) * BK + soff]);
            }
#pragma unroll
            for (int i = 0; i < 4; i++)
#pragma unroll
                for (int j = 0; j < 4; j++)
                    acc[i][j] = __builtin_amdgcn_mfma_f32_16x16x32_bf16(af[i], bfr[j], acc[i][j], 0, 0, 0);
        }
        __syncthreads();
    }

#pragma unroll
    for (int i = 0; i < 4; i++) {
#pragma unroll
        for (int j = 0; j < 4; j++) {
#pragma unroll
            for (int r = 0; r < 4; r++) {
                int grow = row0 + wm + i * 16 + lq * 4 + r;
                int gcol = col0 + wn + j * 16 + lr;
                float c = acc[i][j][r];
                size_t idx = (size_t)grow * N + gcol;
                if (EPI == 0) {
                    outF[idx] = c;
                } else if (EPI == 1) {
                    outF[idx] = c + bias[gcol] + res[idx];
                } else if (EPI == 2) {
                    c += bias[gcol];
                    float gel = 0.5f * c * (1.0f + erff(c * 0.7071067811865475f));
                    outB[idx] = __float2bfloat16(gel);
                } else {
                    outB[idx] = __float2bfloat16(c);
                }
            }
        }
    }
}

extern "C" void kernel_launch(void* const* d_in, const int* in_sizes, int n_in,
                              void* d_out, int out_size, void* d_ws, size_t ws_size,
                              hipStream_t stream) {
    const float* x      = (const float*)d_in[0];
    const float* w_qkv  = (const float*)d_in[1];
    const float* w_proj = (const float*)d_in[2];
    const float* b_proj = (const float*)d_in[3];
    const float* w_ff1  = (const float*)d_in[4];
    const float* b_ff1  = (const float*)d_in[5];
    const float* w_ff2  = (const float*)d_in[6];
    const float* b_ff2  = (const float*)d_in[7];
    const float* g1     = (const float*)d_in[8];
    const float* be1    = (const float*)d_in[9];
    const float* g2     = (const float*)d_in[10];
    const float* be2    = (const float*)d_in[11];
    float* out = (float*)d_out;

    char* ws = (char*)d_ws;
    size_t off = 0;
    auto alloc = [&](size_t bytes) {
        void* p = ws + off;
        off += (bytes + 255) & ~(size_t)255;
        return p;
    };
    bf16*  wqkv_b  = (bf16*)alloc((size_t)3 * D_MODEL * D_MODEL * sizeof(bf16));
    bf16*  wproj_b = (bf16*)alloc((size_t)D_MODEL * D_MODEL * sizeof(bf16));
    bf16*  wff1_b  = (bf16*)alloc((size_t)FFDIM * D_MODEL * sizeof(bf16));
    bf16*  wff2_b  = (bf16*)alloc((size_t)D_MODEL * FFDIM * sizeof(bf16));
    bf16*  qkv_b   = (bf16*)alloc((size_t)TOKENS * FFDIM * sizeof(bf16)); // qkv then ff1 overlay
    bf16*  ff1_b   = qkv_b;
    bf16*  act_b   = (bf16*)alloc((size_t)TOKENS * D_MODEL * sizeof(bf16));
    float* x2_f    = (float*)alloc((size_t)TOKENS * D_MODEL * sizeof(float));
    bf16*  vt_g    = (bf16*)x2_f;    // overlay: Vt dead before proj writes x2 (stream-ordered)

    cast4_kernel<<<N0 + N1 + N2 + N3 >= 0 ? (N0 + N1 + N2 + N3 + 255) / 256 : 0, 256, 0, stream>>>(
        w_qkv, w_proj, w_ff1, w_ff2, wqkv_b, wproj_b, wff1_b, wff2_b);

    ln_kernel<<<TOKENS, 256, 0, stream>>>(x, g1, be1, act_b);

    gemm_bt<3><<<dim3(3 * D_MODEL / BN, TOKENS / BM), 256, 0, stream>>>(
        act_b, wqkv_b, nullptr, nullptr, nullptr, qkv_b, TOKENS, 3 * D_MODEL, D_MODEL);

    rope_kernel<<<TOKENS * N_HEADS / 4, 256, 0, stream>>>(qkv_b);

    vt_kernel<<<dim3(BATCH * N_HEADS, SEQ / 64, D_HEAD / 32), 256, 0, stream>>>(qkv_b, vt_g);

    flash_attn<<<dim3(BATCH * N_HEADS, SEQ / 64), 256, 0, stream>>>(qkv_b, vt_g, act_b);

    gemm_bt<1><<<dim3(D_MODEL / BN, TOKENS / BM), 256, 0, stream>>>(
        act_b, wproj_b, b_proj, x, x2_f, nullptr, TOKENS, D_MODEL, D_MODEL);

    ln_kernel<<<TOKENS, 256, 0, stream>>>(x2_f, g2, be2, act_b);

    gemm_bt<2><<<dim3(FFDIM / BN, TOKENS / BM), 256, 0, stream>>>(
        act_b, wff1_b, b_ff1, nullptr, nullptr, ff1_b, TOKENS, FFDIM, D_MODEL);

    gemm_bt<1><<<dim3(D_MODEL / BN, TOKENS / BM), 256, 0, stream>>>(
        ff1_b, wff2_b, b_ff2, x2_f, out, nullptr, TOKENS, D_MODEL, FFDIM);

    (void)in_sizes; (void)n_in; (void)out_size; (void)ws_size;
}

// Round 5
// 898.265 us; speedup vs baseline: 10.0998x; 1.0264x over previous
//
#include <hip/hip_runtime.h>
#include <hip/hip_bf16.h>
#include <cmath>

#define D_MODEL 2048
#define N_HEADS 16
#define D_HEAD  128
#define FFDIM   8192
#define BATCH   2
#define SEQ     2048
#define TOKENS  (BATCH * SEQ)

using bf16 = __hip_bfloat16;
typedef __bf16 v8bf  __attribute__((ext_vector_type(8)));
typedef float  v4f   __attribute__((ext_vector_type(4)));
typedef float  v16f  __attribute__((ext_vector_type(16)));

// ---------------- fused weight cast f32 -> bf16 (all 4 weight mats) ----------------
#define N0 (3 * D_MODEL * D_MODEL / 4)
#define N1 (D_MODEL * D_MODEL / 4)
#define N2 (FFDIM * D_MODEL / 4)
#define N3 (D_MODEL * FFDIM / 4)

__global__ __launch_bounds__(256) void cast4_kernel(const float* __restrict__ w0,
                                                    const float* __restrict__ w1,
                                                    const float* __restrict__ w2,
                                                    const float* __restrict__ w3,
                                                    bf16* __restrict__ o0,
                                                    bf16* __restrict__ o1,
                                                    bf16* __restrict__ o2,
                                                    bf16* __restrict__ o3) {
    int i = blockIdx.x * 256 + threadIdx.x;
    const float* src; bf16* dst; int j;
    if (i < N0)                { src = w0; dst = o0; j = i; }
    else if (i < N0 + N1)      { src = w1; dst = o1; j = i - N0; }
    else if (i < N0 + N1 + N2) { src = w2; dst = o2; j = i - N0 - N1; }
    else                       { src = w3; dst = o3; j = i - N0 - N1 - N2; }
    float4 f = ((const float4*)src)[j];
    int o = j * 4;
    dst[o + 0] = __float2bfloat16(f.x);
    dst[o + 1] = __float2bfloat16(f.y);
    dst[o + 2] = __float2bfloat16(f.z);
    dst[o + 3] = __float2bfloat16(f.w);
}

// ---------------- LayerNorm (one row per block), fp32 in -> bf16 out ----------------
__global__ __launch_bounds__(256) void ln_kernel(const float* __restrict__ x,
                                                 const float* __restrict__ g,
                                                 const float* __restrict__ b,
                                                 bf16* __restrict__ out) {
    int row = blockIdx.x;
    int t = threadIdx.x;
    const float* xr = x + (size_t)row * D_MODEL;
    float v[8];
    float s = 0.f, s2 = 0.f;
#pragma unroll
    for (int i = 0; i < 8; i++) {
        float val = xr[t + 256 * i];
        v[i] = val;
        s += val;
        s2 += val * val;
    }
#pragma unroll
    for (int off = 32; off > 0; off >>= 1) {
        s  += __shfl_down(s, off, 64);
        s2 += __shfl_down(s2, off, 64);
    }
    __shared__ float ws1[4], ws2[4];
    int wv = t >> 6;
    if ((t & 63) == 0) { ws1[wv] = s; ws2[wv] = s2; }
    __syncthreads();
    float fs  = ws1[0] + ws1[1] + ws1[2] + ws1[3];
    float fs2 = ws2[0] + ws2[1] + ws2[2] + ws2[3];
    float mean = fs * (1.0f / D_MODEL);
    float var  = fs2 * (1.0f / D_MODEL) - mean * mean;
    float rstd = rsqrtf(var + 1e-5f);
    bf16* orow = out + (size_t)row * D_MODEL;
#pragma unroll
    for (int i = 0; i < 8; i++) {
        int c = t + 256 * i;
        orow[c] = __float2bfloat16((v[i] - mean) * rstd * g[c] + b[c]);
    }
}

// ---------------- RoPE in-place on bf16 qkv; folds 1/sqrt(d) into q ----------------
__global__ __launch_bounds__(256) void rope_kernel(bf16* __restrict__ qkv) {
    int unit = blockIdx.x * 4 + (threadIdx.x >> 6);
    int j = threadIdx.x & 63;
    int h = unit & (N_HEADS - 1);
    int tok = unit >> 4;
    int pos = tok & (SEQ - 1);
    float invf = powf(10000.0f, -(float)j / 64.0f);
    float ang = (float)pos * invf;
    float c = cosf(ang), s = sinf(ang);
    const float sc = 0.08838834764831845f; // 1/sqrt(128), folded into q
    size_t base = (size_t)tok * (3 * D_MODEL) + h * D_HEAD;
    float q1 = __bfloat162float(qkv[base + j]), q2 = __bfloat162float(qkv[base + j + 64]);
    qkv[base + j]      = __float2bfloat16((q1 * c - q2 * s) * sc);
    qkv[base + j + 64] = __float2bfloat16((q2 * c + q1 * s) * sc);
    size_t kb = base + D_MODEL;
    float k1 = __bfloat162float(qkv[kb + j]), k2 = __bfloat162float(qkv[kb + j + 64]);
    qkv[kb + j]      = __float2bfloat16(k1 * c - k2 * s);
    qkv[kb + j + 64] = __float2bfloat16(k2 * c + k1 * s);
}

// ---------------- V transpose: qkv bf16 [tok][3D] -> Vt bf16 [bh][d][k] ----------------
__global__ __launch_bounds__(256) void vt_kernel(const bf16* __restrict__ qkv,
                                                 bf16* __restrict__ vt) {
    __shared__ float tile[32][65];
    int bh = blockIdx.x;
    int k0 = blockIdx.y * 64;
    int d0 = blockIdx.z * 32;
    int b = bh >> 4, h = bh & 15;
    int t = threadIdx.x;
    const bf16* src = qkv + ((size_t)b * SEQ + k0) * (3 * D_MODEL) + 2 * D_MODEL + h * D_HEAD + d0;
#pragma unroll
    for (int i = 0; i < 8; i++) {
        int e = t + 256 * i;
        int kr = e >> 5, dc = e & 31;
        tile[dc][kr] = __bfloat162float(src[(size_t)kr * (3 * D_MODEL) + dc]);
    }
    __syncthreads();
    bf16* dst = vt + ((size_t)bh * D_HEAD + d0) * SEQ + k0;
#pragma unroll
    for (int i = 0; i < 8; i++) {
        int e = t + 256 * i;
        int dr = e >> 6, kc = e & 63;
        dst[(size_t)dr * SEQ + kc] = __float2bfloat16(tile[dr][kc]);
    }
}

// ---------------- flash attention: MFMA, online softmax, bf16 qkv ----------------
#define KS_STRIDE 136
#define VT_STRIDE 72
#define PS_STRIDE 72

__global__ __launch_bounds__(256) void flash_attn(const bf16* __restrict__ qkv,
                                                  const bf16* __restrict__ vt,
                                                  bf16* __restrict__ att) {
    __shared__ __align__(16) bf16 Ks[64 * KS_STRIDE];       // [kpos][d] padded
    __shared__ __align__(16) bf16 Vts[D_HEAD * VT_STRIDE];  // [d][kpos] padded
    __shared__ __align__(16) bf16 Ps[4 * 16 * PS_STRIDE];   // per-wave [q][kpos]

    int bh = blockIdx.x;
    int qt = (int)gridDim.y - 1 - (int)blockIdx.y;  // heavy q-tiles first
    int b = bh >> 4, h = bh & 15;
    int t = threadIdx.x, wave = t >> 6, lane = t & 63;
    int lr = lane & 15, lq = lane >> 4;

    const bf16* qp = qkv + ((size_t)b * SEQ + qt * 64 + wave * 16 + lr) * (3 * D_MODEL) + h * D_HEAD;
    v8bf aq[4];
#pragma unroll
    for (int c = 0; c < 4; c++)
        aq[c] = *(const v8bf*)(qp + c * 32 + lq * 8);

    float m_r[4], l_r[4];
    v4f O[8] = {};
#pragma unroll
    for (int r = 0; r < 4; r++) { m_r[r] = -1e30f; l_r[r] = 0.f; }

    int n_tiles = qt + 1;
    for (int kt = 0; kt < n_tiles; kt++) {
        int kv0 = kt * 64;
        __syncthreads();
        {
            const bf16* kbase = qkv + ((size_t)b * SEQ + kv0) * (3 * D_MODEL) + D_MODEL + h * D_HEAD;
#pragma unroll
            for (int i = 0; i < 4; i++) {
                int e = t + 256 * i;
                int kr = e >> 4, c8 = (e & 15) * 8;
                *(uint4*)&Ks[kr * KS_STRIDE + c8] = *(const uint4*)(kbase + (size_t)kr * (3 * D_MODEL) + c8);
            }
            const bf16* vbase = vt + (size_t)bh * D_HEAD * SEQ + kv0;
#pragma unroll
            for (int i = 0; i < 4; i++) {
                int e8 = t + 256 * i;
                int dr = e8 >> 3, k8 = (e8 & 7) * 8;
                *(uint4*)&Vts[dr * VT_STRIDE + k8] = *(const uint4*)(vbase + (size_t)dr * SEQ + k8);
            }
        }
        __syncthreads();

        v4f sc[4];
#pragma unroll
        for (int nt = 0; nt < 4; nt++) {
            v4f a = {};
#pragma unroll
            for (int c = 0; c < 4; c++) {
                v8bf bk = *(const v8bf*)&Ks[(nt * 16 + lr) * KS_STRIDE + c * 32 + lq * 8];
                a = __builtin_amdgcn_mfma_f32_16x16x32_bf16(aq[c], bk, a, 0, 0, 0);
            }
            sc[nt] = a;
        }
        if (kt == n_tiles - 1) {
#pragma unroll
            for (int nt = 0; nt < 4; nt++)
#pragma unroll
                for (int r = 0; r < 4; r++) {
                    int cl = nt * 16 + lr, rl = wave * 16 + lq * 4 + r;
                    if (cl > rl) sc[nt][r] = -1e30f;
                }
        }
        float mt[4];
#pragma unroll
        for (int r = 0; r < 4; r++) {
            float v = fmaxf(fmaxf(sc[0][r], sc[1][r]), fmaxf(sc[2][r], sc[3][r]));
#pragma unroll
            for (int mk = 8; mk >= 1; mk >>= 1) v = fmaxf(v, __shfl_xor(v, mk, 64));
            mt[r] = v;
        }
        float alpha[4];
#pragma unroll
        for (int r = 0; r < 4; r++) {
            float mn = fmaxf(m_r[r], mt[r]);
            alpha[r] = __expf(m_r[r] - mn);
            m_r[r] = mn;
        }
        bf16* pw = &Ps[wave * 16 * PS_STRIDE];
        float rs[4] = {0.f, 0.f, 0.f, 0.f};
#pragma unroll
        for (int nt = 0; nt < 4; nt++)
#pragma unroll
            for (int r = 0; r < 4; r++) {
                float p = __expf(sc[nt][r] - m_r[r]);
                rs[r] += p;
                pw[(lq * 4 + r) * PS_STRIDE + nt * 16 + lr] = __float2bfloat16(p);
            }
#pragma unroll
        for (int r = 0; r < 4; r++) {
            float v = rs[r];
#pragma unroll
            for (int mk = 8; mk >= 1; mk >>= 1) v += __shfl_xor(v, mk, 64);
            l_r[r] = l_r[r] * alpha[r] + v;
        }
#pragma unroll
        for (int jt = 0; jt < 8; jt++)
#pragma unroll
            for (int r = 0; r < 4; r++) O[jt][r] *= alpha[r];

        asm volatile("s_waitcnt lgkmcnt(0)" ::: "memory");

        v8bf ap[2];
#pragma unroll
        for (int c = 0; c < 2; c++)
            ap[c] = *(const v8bf*)&pw[lr * PS_STRIDE + c * 32 + lq * 8];
#pragma unroll
        for (int jt = 0; jt < 8; jt++) {
#pragma unroll
            for (int c = 0; c < 2; c++) {
                v8bf bv = *(const v8bf*)&Vts[(jt * 16 + lr) * VT_STRIDE + c * 32 + lq * 8];
                O[jt] = __builtin_amdgcn_mfma_f32_16x16x32_bf16(ap[c], bv, O[jt], 0, 0, 0);
            }
        }
    }

    float inv[4];
#pragma unroll
    for (int r = 0; r < 4; r++) inv[r] = 1.0f / l_r[r];
#pragma unroll
    for (int jt = 0; jt < 8; jt++)
#pragma unroll
        for (int r = 0; r < 4; r++) {
            size_t idx = ((size_t)b * SEQ + qt * 64 + wave * 16 + lq * 4 + r) * D_MODEL + h * D_HEAD + jt * 16 + lr;
            att[idx] = __float2bfloat16(O[jt][r] * inv[r]);
        }
}

// ---------------- bf16 MFMA GEMM: 32x32x16 MFMA, BK=64, XOR-swizzled LDS, DMA staging ----
// EPI 0: fp32 out | 1: +bias+residual fp32 | 2: +bias,GELU bf16 | 3: plain bf16
#define BM 128
#define BN 128
#define BK 64

template <int EPI>
__global__ __launch_bounds__(256) void gemm_bt(const bf16* __restrict__ A,
                                               const bf16* __restrict__ W,
                                               const float* __restrict__ bias,
                                               const float* __restrict__ res,
                                               float* __restrict__ outF,
                                               bf16* __restrict__ outB,
                                               int M, int N, int K) {
    __shared__ __align__(16) bf16 As[BM * BK];  // 16 KB, XOR-swizzled 16B blocks within rows
    __shared__ __align__(16) bf16 Bs[BN * BK];  // 16 KB
    int t = threadIdx.x;
    int wave = t >> 6, lane = t & 63;
    int wm = (wave >> 1) * 64;
    int wn = (wave & 1) * 64;
    int l31 = lane & 31;   // 32x32 operand row (m or n)
    int kh  = lane >> 5;   // k half (0/1) within 16-k step

    // ---- block swizzle: XCD-contiguous remap, then 8-M-tile panel, column-major ----
    int nbx = gridDim.x;
    int bid = (int)blockIdx.y * nbx + (int)blockIdx.x;
    int per = (nbx * (int)gridDim.y) >> 3;
    int lbid = (bid & 7) * per + (bid >> 3);
    const int GM = 8;
    int pw = GM * nbx;
    int panel = lbid / pw;
    int rem = lbid - panel * pw;
    int bm = panel * GM + (rem & (GM - 1));
    int bn = rem >> 3;
    int row0 = bm * BM;
    int col0 = bn * BN;

    // staging lane geometry: chunk = 8 rows x 64 cols (1KB); LDS block b of row r holds
    // global k-block (b ^ (r&7)).
    int srow = lane >> 3;             // 0..7
    int sblk = lane & 7;              // dest 16B block
    int scol = ((sblk ^ srow) * 8);   // source k element offset

    v16f acc[2][2] = {};

    for (int k0 = 0; k0 < K; k0 += BK) {
#pragma unroll
        for (int u = 0; u < 4; u++) {
            int c = wave * 4 + u;     // chunk 0..15
            const bf16* ga = A + (size_t)(row0 + c * 8 + srow) * K + k0 + scol;
            __builtin_amdgcn_global_load_lds(
                (const __attribute__((address_space(1))) void*)ga,
                (__attribute__((address_space(3))) void*)&As[c * 512], 16, 0, 0);
            const bf16* gb = W + (size_t)(col0 + c * 8 + srow) * K + k0 + scol;
            __builtin_amdgcn_global_load_lds(
                (const __attribute__((address_space(1))) void*)gb,
                (__attribute__((address_space(3))) void*)&Bs[c * 512], 16, 0, 0);
        }
        __syncthreads();
#pragma unroll
        for (int ks = 0; ks < 4; ks++) {       // four 16-k steps
            // A/B frag: row = wm/wn + ti*32 + l31; k = ks*16 + kh*8 + j
            // swizzled 16B block: (ks*2 + kh) ^ (row&7); row&7 == lane&7 (wm,ti*32 are mult of 8)
            int soff = (((ks * 2 + kh) ^ (lane & 7)) * 8);
            v8bf a0 = *(const v8bf*)(&As[(wm +      l31) * BK + soff]);
            v8bf a1 = *(const v8bf*)(&As[(wm + 32 + l31) * BK + soff]);
            v8bf b0 = *(const v8bf*)(&Bs[(wn +      l31) * BK + soff]);
            v8bf b1 = *(const v8bf*)(&Bs[(wn + 32 + l31) * BK + soff]);
            acc[0][0] = __builtin_amdgcn_mfma_f32_32x32x16_bf16(a0, b0, acc[0][0], 0, 0, 0);
            acc[0][1] = __builtin_amdgcn_mfma_f32_32x32x16_bf16(a0, b1, acc[0][1], 0, 0, 0);
            acc[1][0] = __builtin_amdgcn_mfma_f32_32x32x16_bf16(a1, b0, acc[1][0], 0, 0, 0);
            acc[1][1] = __builtin_amdgcn_mfma_f32_32x32x16_bf16(a1, b1, acc[1][1], 0, 0, 0);
        }
        __syncthreads();
    }

    // epilogue: C/D layout col = lane&31, row = (reg&3) + 8*(reg>>2) + 4*(lane>>5)
#pragma unroll
    for (int ti = 0; ti < 2; ti++) {
#pragma unroll
        for (int tj = 0; tj < 2; tj++) {
#pragma unroll
            for (int reg = 0; reg < 16; reg++) {
                int grow = row0 + wm + ti * 32 + (reg & 3) + 8 * (reg >> 2) + 4 * kh;
                int gcol = col0 + wn + tj * 32 + l31;
                float c = acc[ti][tj][reg];
                size_t idx = (size_t)grow * N + gcol;
                if (EPI == 0) {
                    outF[idx] = c;
                } else if (EPI == 1) {
                    outF[idx] = c + bias[gcol] + res[idx];
                } else if (EPI == 2) {
                    c += bias[gcol];
                    float gel = 0.5f * c * (1.0f + erff(c * 0.7071067811865475f));
                    outB[idx] = __float2bfloat16(gel);
                } else {
                    outB[idx] = __float2bfloat16(c);
                }
            }
        }
    }
}

extern "C" void kernel_launch(void* const* d_in, const int* in_sizes, int n_in,
                              void* d_out, int out_size, void* d_ws, size_t ws_size,
                              hipStream_t stream) {
    const float* x      = (const float*)d_in[0];
    const float* w_qkv  = (const float*)d_in[1];
    const float* w_proj = (const float*)d_in[2];
    const float* b_proj = (const float*)d_in[3];
    const float* w_ff1  = (const float*)d_in[4];
    const float* b_ff1  = (const float*)d_in[5];
    const float* w_ff2  = (const float*)d_in[6];
    const float* b_ff2  = (const float*)d_in[7];
    const float* g1     = (const float*)d_in[8];
    const float* be1    = (const float*)d_in[9];
    const float* g2     = (const float*)d_in[10];
    const float* be2    = (const float*)d_in[11];
    float* out = (float*)d_out;

    char* ws = (char*)d_ws;
    size_t off = 0;
    auto alloc = [&](size_t bytes) {
        void* p = ws + off;
        off += (bytes + 255) & ~(size_t)255;
        return p;
    };
    bf16*  wqkv_b  = (bf16*)alloc((size_t)3 * D_MODEL * D_MODEL * sizeof(bf16));
    bf16*  wproj_b = (bf16*)alloc((size_t)D_MODEL * D_MODEL * sizeof(bf16));
    bf16*  wff1_b  = (bf16*)alloc((size_t)FFDIM * D_MODEL * sizeof(bf16));
    bf16*  wff2_b  = (bf16*)alloc((size_t)D_MODEL * FFDIM * sizeof(bf16));
    bf16*  qkv_b   = (bf16*)alloc((size_t)TOKENS * FFDIM * sizeof(bf16)); // qkv then ff1 overlay
    bf16*  ff1_b   = qkv_b;
    bf16*  act_b   = (bf16*)alloc((size_t)TOKENS * D_MODEL * sizeof(bf16));
    float* x2_f    = (float*)alloc((size_t)TOKENS * D_MODEL * sizeof(float));
    bf16*  vt_g    = (bf16*)x2_f;    // overlay: Vt dead before proj writes x2 (stream-ordered)

    cast4_kernel<<<(N0 + N1 + N2 + N3 + 255) / 256, 256, 0, stream>>>(
        w_qkv, w_proj, w_ff1, w_ff2, wqkv_b, wproj_b, wff1_b, wff2_b);

    ln_kernel<<<TOKENS, 256, 0, stream>>>(x, g1, be1, act_b);

    gemm_bt<3><<<dim3(3 * D_MODEL / BN, TOKENS / BM), 256, 0, stream>>>(
        act_b, wqkv_b, nullptr, nullptr, nullptr, qkv_b, TOKENS, 3 * D_MODEL, D_MODEL);

    rope_kernel<<<TOKENS * N_HEADS / 4, 256, 0, stream>>>(qkv_b);

    vt_kernel<<<dim3(BATCH * N_HEADS, SEQ / 64, D_HEAD / 32), 256, 0, stream>>>(qkv_b, vt_g);

    flash_attn<<<dim3(BATCH * N_HEADS, SEQ / 64), 256, 0, stream>>>(qkv_b, vt_g, act_b);

    gemm_bt<1><<<dim3(D_MODEL / BN, TOKENS / BM), 256, 0, stream>>>(
        act_b, wproj_b, b_proj, x, x2_f, nullptr, TOKENS, D_MODEL, D_MODEL);

    ln_kernel<<<TOKENS, 256, 0, stream>>>(x2_f, g2, be2, act_b);

    gemm_bt<2><<<dim3(FFDIM / BN, TOKENS / BM), 256, 0, stream>>>(
        act_b, wff1_b, b_ff1, nullptr, nullptr, ff1_b, TOKENS, FFDIM, D_MODEL);

    gemm_bt<1><<<dim3(D_MODEL / BN, TOKENS / BM), 256, 0, stream>>>(
        ff1_b, wff2_b, b_ff2, x2_f, out, nullptr, TOKENS, D_MODEL, FFDIM);

    (void)in_sizes; (void)n_in; (void)out_size; (void)ws_size;
}